// Round 1
// baseline (8492.021 us; speedup 1.0000x reference)
//
#include <hip/hip_runtime.h>
#include <hip/hip_bf16.h>

#define NN 100000
#define EE 3200000
#define RR_ 8
#define NSEG (NN * RR_)
#define APAD 136  // LDS row pad: granule stride 34 -> 2-bank lane step, 2-way = free

static __device__ __forceinline__ float frelu(float v) { return v > 0.f ? v : 0.f; }

// ---------- x = node_emb[node_type_ids] ----------
__global__ void k_gather_x(const int* __restrict__ ntype, const float* __restrict__ nemb,
                           float* __restrict__ x) {
    int i = blockIdx.x * 256 + threadIdx.x;   // exactly N*32 threads
    int n = i >> 5, q = i & 31;
    int tt = ntype[n];
    ((float4*)x)[(size_t)n * 32 + q] = ((const float4*)nemb)[tt * 32 + q];
}

// ---------- CSR build: count / scan / scatter ----------
__global__ void k_count(const int* __restrict__ eidx, const int* __restrict__ etype,
                        int* __restrict__ cnt) {
    for (int e = blockIdx.x * blockDim.x + threadIdx.x; e < EE; e += gridDim.x * blockDim.x) {
        int tgt = eidx[2 * e + 1];
        atomicAdd(&cnt[etype[e] * NN + tgt], 1);
    }
}

__global__ void k_scan1(const int* __restrict__ cnt, int* __restrict__ rowptr,
                        int* __restrict__ partials, int nseg) {
    __shared__ int sd[256];
    int t = threadIdx.x;
    int base = blockIdx.x * 1024 + t * 4;
    int v[4];
#pragma unroll
    for (int k = 0; k < 4; ++k) v[k] = (base + k < nseg) ? cnt[base + k] : 0;
    int tsum = v[0] + v[1] + v[2] + v[3];
    sd[t] = tsum;
    __syncthreads();
    for (int off = 1; off < 256; off <<= 1) {
        int add = (t >= off) ? sd[t - off] : 0;
        __syncthreads();
        sd[t] += add;
        __syncthreads();
    }
    int excl = sd[t] - tsum;
    int run = excl;
#pragma unroll
    for (int k = 0; k < 4; ++k) {
        if (base + k < nseg) rowptr[base + k] = run;
        run += v[k];
    }
    if (t == 255) partials[blockIdx.x] = sd[255];
}

__global__ void k_scan2(int* __restrict__ partials, int nb) {
    __shared__ int sd[1024];
    int t = threadIdx.x;
    int v = (t < nb) ? partials[t] : 0;
    sd[t] = v;
    __syncthreads();
    for (int off = 1; off < 1024; off <<= 1) {
        int add = (t >= off) ? sd[t - off] : 0;
        __syncthreads();
        sd[t] += add;
        __syncthreads();
    }
    if (t < nb) partials[t] = sd[t] - v;   // exclusive block offsets
}

__global__ void k_scan3(int* __restrict__ rowptr, int* __restrict__ cursor,
                        const int* __restrict__ partials, int nseg) {
    int i = blockIdx.x * 256 + threadIdx.x;
    if (i < nseg) {
        int r = rowptr[i] + partials[i >> 10];
        rowptr[i] = r;
        cursor[i] = r;
    } else if (i == nseg) {
        rowptr[i] = EE;
    }
}

__global__ void k_scatter(const int* __restrict__ eidx, const int* __restrict__ etype,
                          int* __restrict__ cursor, int* __restrict__ esrc) {
    for (int e = blockIdx.x * blockDim.x + threadIdx.x; e < EE; e += gridDim.x * blockDim.x) {
        int src = eidx[2 * e];
        int tgt = eidx[2 * e + 1];
        int s = etype[e] * NN + tgt;
        int pos = atomicAdd(&cursor[s], 1);
        esrc[pos] = src;
    }
}

// ---------- fused layer: per block 64 nodes; rr=0..7 relation agg+GEMM, rr=8 self ----------
__global__ __launch_bounds__(256, 4) void k_layer(
    const float* __restrict__ x, const int* __restrict__ rowptr, const int* __restrict__ esrc,
    const float* __restrict__ relW,   // (8,128,128) this layer
    const float* __restrict__ selfW,  // (128,128)
    const float* __restrict__ selfb,  // (128)
    float* __restrict__ xout) {
    __shared__ float tile[64 * APAD];
    const int t = threadIdx.x;
    const int lane = t & 63;
    const int wave = t >> 6;           // 4 waves, 16 nodes each (gather phase)
    const int p = t & 31, g = t >> 5;  // GEMM: rows {p, p+32}, cols [16g,16g+16)
    const int node0 = blockIdx.x * 64;

    float acc[2][16];
#pragma unroll
    for (int i = 0; i < 2; ++i)
#pragma unroll
        for (int j = 0; j < 16; ++j) acc[i][j] = 0.f;

    for (int rr = 0; rr < 9; ++rr) {
        __syncthreads();  // protect tile from previous GEMM reads
        // ---- gather phase: fill LDS tile with agg rows (or x rows for self) ----
        for (int i = 0; i < 16; ++i) {
            int lr = wave * 16 + i;
            int n = node0 + lr;
            float ax = 0.f, ay = 0.f;
            if (n < NN) {
                if (rr < 8) {
                    int s = rr * NN + n;
                    int beg = rowptr[s], end = rowptr[s + 1];
                    int j = beg;
                    for (; j + 4 <= end; j += 4) {   // 4 loads in flight
                        int s0 = esrc[j], s1 = esrc[j + 1], s2 = esrc[j + 2], s3 = esrc[j + 3];
                        float2 v0 = ((const float2*)(x + (size_t)s0 * 128))[lane];
                        float2 v1 = ((const float2*)(x + (size_t)s1 * 128))[lane];
                        float2 v2 = ((const float2*)(x + (size_t)s2 * 128))[lane];
                        float2 v3 = ((const float2*)(x + (size_t)s3 * 128))[lane];
                        ax += (v0.x + v1.x) + (v2.x + v3.x);
                        ay += (v0.y + v1.y) + (v2.y + v3.y);
                    }
                    for (; j < end; ++j) {
                        float2 v = ((const float2*)(x + (size_t)esrc[j] * 128))[lane];
                        ax += v.x;
                        ay += v.y;
                    }
                } else {
                    float2 v = ((const float2*)(x + (size_t)n * 128))[lane];
                    ax = v.x;
                    ay = v.y;
                }
            }
            tile[lr * APAD + 2 * lane] = ax;
            tile[lr * APAD + 2 * lane + 1] = ay;
        }
        __syncthreads();
        // ---- GEMM phase: acc += tile @ W^T ----
        const float* __restrict__ W = (rr < 8) ? (relW + (size_t)rr * 128 * 128) : selfW;
#pragma unroll 4
        for (int h4 = 0; h4 < 32; ++h4) {
            float4 a0 = *(const float4*)&tile[p * APAD + h4 * 4];
            float4 a1 = *(const float4*)&tile[(p + 32) * APAD + h4 * 4];
#pragma unroll
            for (int j = 0; j < 16; ++j) {
                float4 w = *(const float4*)&W[(size_t)(16 * g + j) * 128 + h4 * 4];
                acc[0][j] += a0.x * w.x + a0.y * w.y + a0.z * w.z + a0.w * w.w;
                acc[1][j] += a1.x * w.x + a1.y * w.y + a1.z * w.z + a1.w * w.w;
            }
        }
    }
    // ---- epilogue: bias + relu + store ----
#pragma unroll
    for (int i = 0; i < 2; ++i) {
        int n = node0 + p + 32 * i;
        if (n < NN) {
#pragma unroll
            for (int j4 = 0; j4 < 4; ++j4) {
                float4 b = *(const float4*)&selfb[16 * g + 4 * j4];
                float4 o;
                o.x = frelu(acc[i][4 * j4 + 0] + b.x);
                o.y = frelu(acc[i][4 * j4 + 1] + b.y);
                o.z = frelu(acc[i][4 * j4 + 2] + b.z);
                o.w = frelu(acc[i][4 * j4 + 3] + b.w);
                *(float4*)&xout[(size_t)n * 128 + 16 * g + 4 * j4] = o;
            }
        }
    }
}

// ---------- column-wise sum/max over final x ----------
__global__ void k_reduce(const float* __restrict__ x, float* __restrict__ gsum,
                         unsigned* __restrict__ gmax) {
    int c = threadIdx.x & 127;
    int half = threadIdx.x >> 7;
    int rbeg = blockIdx.x * 512 + half;
    int rend = min(blockIdx.x * 512 + 512, NN);
    float s = 0.f, m = 0.f;  // post-relu values >= 0
    for (int r = rbeg; r < rend; r += 2) {
        float v = x[(size_t)r * 128 + c];
        s += v;
        m = fmaxf(m, v);
    }
    atomicAdd(&gsum[c], s);
    atomicMax(&gmax[c], __float_as_uint(m));  // valid: all values >= 0
}

// ---------- heads (single block) ----------
__global__ void k_head(const float* __restrict__ x, const float* __restrict__ gsum,
                       const unsigned* __restrict__ gmaxu, const int* __restrict__ anchor_idx,
                       const float* __restrict__ numeric, const float* __restrict__ boolean_,
                       const int* __restrict__ cats, const float* __restrict__ ce0,
                       const float* __restrict__ ce1, const float* __restrict__ ce2,
                       const float* __restrict__ featW, const float* __restrict__ featb,
                       const float* __restrict__ binW1, const float* __restrict__ binb1,
                       const float* __restrict__ binW2, const float* __restrict__ binb2,
                       const float* __restrict__ mcW1, const float* __restrict__ mcb1,
                       const float* __restrict__ mcW2, const float* __restrict__ mcb2,
                       float* __restrict__ out) {
    __shared__ float comb[432];
    __shared__ float feat[72];
    __shared__ float hb[4][64];
    int t = threadIdx.x;
    int anchor = anchor_idx[0];
    if (t < 128) {
        comb[t] = x[(size_t)anchor * 128 + t];
        comb[128 + t] = gsum[t] * (1.0f / (float)NN);
        comb[256 + t] = __uint_as_float(gmaxu[t]);
    }
    if (t < 32) feat[t] = numeric[t];
    else if (t < 48) feat[t] = boolean_[t - 32];
    else if (t < 56) feat[t] = ce0[cats[0] * 8 + (t - 48)];
    else if (t < 64) feat[t] = ce1[cats[1] * 8 + (t - 56)];
    else if (t < 72) feat[t] = ce2[cats[2] * 8 + (t - 64)];
    __syncthreads();
    if (t < 48) {
        float s = featb[t];
        for (int c = 0; c < 72; ++c) s += featW[t * 72 + c] * feat[c];
        comb[384 + t] = frelu(s);
    }
    __syncthreads();
    {
        int head = t >> 6, u = t & 63;
        const float* W;
        float s;
        if (head < 3) {
            W = binW1 + ((size_t)head * 64 + u) * 432;
            s = binb1[head * 64 + u];
        } else {
            W = mcW1 + (size_t)u * 432;
            s = mcb1[u];
        }
        for (int c = 0; c < 432; ++c) s += W[c] * comb[c];
        hb[head][u] = frelu(s);
    }
    __syncthreads();
    if (t < 3) {
        float s = binb2[t];
        for (int u = 0; u < 64; ++u) s += binW2[t * 64 + u] * hb[t][u];
        out[t] = s;
    } else if (t < 7) {
        int k = t - 3;
        float s = mcb2[k];
        for (int u = 0; u < 64; ++u) s += mcW2[k * 64 + u] * hb[3][u];
        out[3 + k] = s;
    }
}

extern "C" void kernel_launch(void* const* d_in, const int* in_sizes, int n_in,
                              void* d_out, int out_size, void* d_ws, size_t ws_size,
                              hipStream_t stream) {
    const int* ntype = (const int*)d_in[0];
    const int* eidx = (const int*)d_in[1];
    const int* etype = (const int*)d_in[2];
    const int* cats = (const int*)d_in[3];
    const int* anchor = (const int*)d_in[4];
    const float* numeric = (const float*)d_in[5];
    const float* boolean_ = (const float*)d_in[6];
    const float* nemb = (const float*)d_in[7];
    const float* selfW = (const float*)d_in[8];
    const float* selfb = (const float*)d_in[9];
    const float* relW = (const float*)d_in[10];
    const float* ce0 = (const float*)d_in[11];
    const float* ce1 = (const float*)d_in[12];
    const float* ce2 = (const float*)d_in[13];
    const float* featW = (const float*)d_in[14];
    const float* featb = (const float*)d_in[15];
    const float* binW1 = (const float*)d_in[16];
    const float* binb1 = (const float*)d_in[17];
    const float* binW2 = (const float*)d_in[18];
    const float* binb2 = (const float*)d_in[19];
    const float* mcW1 = (const float*)d_in[20];
    const float* mcb1 = (const float*)d_in[21];
    const float* mcW2 = (const float*)d_in[22];
    const float* mcb2 = (const float*)d_in[23];
    float* out = (float*)d_out;

    char* ws = (char*)d_ws;
    size_t off = 0;
    auto alloc = [&](size_t bytes) -> void* {
        void* pp = ws + off;
        off += (bytes + 255) & ~(size_t)255;
        return pp;
    };
    float* bufA = (float*)alloc((size_t)NN * 128 * 4);
    float* bufB = (float*)alloc((size_t)NN * 128 * 4);
    int* cnt = (int*)alloc((size_t)NSEG * 4);
    int* rowptr = (int*)alloc((size_t)(NSEG + 1) * 4);
    int* cursor = (int*)alloc((size_t)NSEG * 4);
    int* partials = (int*)alloc(4096);
    int* esrc = (int*)alloc((size_t)EE * 4);
    float* gsum = (float*)alloc(512);
    unsigned* gmax = (unsigned*)alloc(512);
    (void)ws_size; (void)in_sizes; (void)n_in; (void)out_size;

    hipMemsetAsync(cnt, 0, (size_t)NSEG * 4, stream);
    hipMemsetAsync(gsum, 0, 512, stream);
    hipMemsetAsync(gmax, 0, 512, stream);

    k_gather_x<<<NN * 32 / 256, 256, 0, stream>>>(ntype, nemb, bufA);
    k_count<<<2048, 256, 0, stream>>>(eidx, etype, cnt);
    int nb1 = (NSEG + 1023) / 1024;
    k_scan1<<<nb1, 256, 0, stream>>>(cnt, rowptr, partials, NSEG);
    k_scan2<<<1, 1024, 0, stream>>>(partials, nb1);
    k_scan3<<<(NSEG + 1 + 255) / 256, 256, 0, stream>>>(rowptr, cursor, partials, NSEG);
    k_scatter<<<2048, 256, 0, stream>>>(eidx, etype, cursor, esrc);

    int lblocks = (NN + 63) / 64;
    k_layer<<<lblocks, 256, 0, stream>>>(bufA, rowptr, esrc, relW, selfW, selfb, bufB);
    k_layer<<<lblocks, 256, 0, stream>>>(bufB, rowptr, esrc, relW + 8 * 128 * 128,
                                         selfW + 128 * 128, selfb + 128, bufA);

    k_reduce<<<(NN + 511) / 512, 256, 0, stream>>>(bufA, gsum, gmax);
    k_head<<<1, 256, 0, stream>>>(bufA, gsum, gmax, anchor, numeric, boolean_, cats, ce0, ce1,
                                  ce2, featW, featb, binW1, binb1, binW2, binb2, mcW1, mcb1,
                                  mcW2, mcb2, out);
}

// Round 4
// 2222.342 us; speedup vs baseline: 3.8212x; 3.8212x over previous
//
#include <hip/hip_runtime.h>
#include <hip/hip_bf16.h>

// R4 = R3 resubmitted unchanged (R3 failed on infra: "container failed twice",
// no pytest output). Audit found no device-side defect; footprint 114 MiB fits
// the ws_size lower bound (~125 MB) proven by R1.

#define NN 100000
#define EE 3200000
#define RR_ 8
#define NSEG (NN * RR_)
#define KTOT 1152   // 8*128 rel + 128 self

static __device__ __forceinline__ float frelu(float v) { return v > 0.f ? v : 0.f; }

// ---------- x = node_emb[node_type_ids] ----------
__global__ void k_gather_x(const int* __restrict__ ntype, const float* __restrict__ nemb,
                           float* __restrict__ x) {
    int i = blockIdx.x * 256 + threadIdx.x;   // exactly N*32 threads
    int n = i >> 5, q = i & 31;
    int tt = ntype[n];
    ((float4*)x)[(size_t)n * 32 + q] = ((const float4*)nemb)[tt * 32 + q];
}

// ---------- CSR build (in-place in rowptr; no cnt/cursor buffers) ----------
__global__ void k_count(const int* __restrict__ eidx, const int* __restrict__ etype,
                        int* __restrict__ rowptr) {
    for (int e = blockIdx.x * blockDim.x + threadIdx.x; e < EE; e += gridDim.x * blockDim.x) {
        int tgt = eidx[2 * e + 1];
        atomicAdd(&rowptr[etype[e] * NN + tgt], 1);
    }
}

// in-place exclusive scan over 1024-element tiles (data read before written per thread)
__global__ void k_scan1(int* data, int* partials, int nseg) {
    __shared__ int sd[256];
    int t = threadIdx.x;
    int base = blockIdx.x * 1024 + t * 4;
    int v[4];
#pragma unroll
    for (int k = 0; k < 4; ++k) v[k] = (base + k < nseg) ? data[base + k] : 0;
    int tsum = v[0] + v[1] + v[2] + v[3];
    sd[t] = tsum;
    __syncthreads();
    for (int off = 1; off < 256; off <<= 1) {
        int add = (t >= off) ? sd[t - off] : 0;
        __syncthreads();
        sd[t] += add;
        __syncthreads();
    }
    int run = sd[t] - tsum;
#pragma unroll
    for (int k = 0; k < 4; ++k) {
        if (base + k < nseg) data[base + k] = run;
        run += v[k];
    }
    if (t == 255) partials[blockIdx.x] = sd[255];
}

__global__ void k_scan2(int* partials, int nb) {
    __shared__ int sd[1024];
    int t = threadIdx.x;
    int v = (t < nb) ? partials[t] : 0;
    sd[t] = v;
    __syncthreads();
    for (int off = 1; off < 1024; off <<= 1) {
        int add = (t >= off) ? sd[t - off] : 0;
        __syncthreads();
        sd[t] += add;
        __syncthreads();
    }
    if (t < nb) partials[t] = sd[t] - v;   // exclusive block offsets
}

__global__ void k_scan3(int* rowptr, const int* __restrict__ partials, int nseg) {
    int i = blockIdx.x * 256 + threadIdx.x;
    if (i < nseg) rowptr[i] += partials[i >> 10];
}

// scatter; rowptr entries become inclusive segment ENDS afterwards
__global__ void k_scatter(const int* __restrict__ eidx, const int* __restrict__ etype,
                          int* rowptr, int* __restrict__ esrc) {
    for (int e = blockIdx.x * blockDim.x + threadIdx.x; e < EE; e += gridDim.x * blockDim.x) {
        int src = eidx[2 * e];
        int tgt = eidx[2 * e + 1];
        int s = etype[e] * NN + tgt;
        int pos = atomicAdd(&rowptr[s], 1);
        esrc[pos] = src;
    }
}

// ---------- W' prep: Wp[l][k][d]; k=r*128+i -> relW[l][r][d][i]; k=1024+i -> selfW[l][d][i]
__global__ void k_prepW(const float* __restrict__ relW, const float* __restrict__ selfW,
                        float* __restrict__ Wp) {
    int idx = blockIdx.x * 256 + threadIdx.x;   // 2*1152*128 threads
    int d = idx & 127;
    int k = (idx >> 7) % KTOT;
    int l = idx / (KTOT * 128);
    float v;
    if (k < 1024) {
        int r = k >> 7, i = k & 127;
        v = relW[(((size_t)l * 8 + r) * 128 + d) * 128 + i];
    } else {
        int i = k - 1024;
        v = selfW[((size_t)l * 128 + d) * 128 + i];
    }
    Wp[idx] = v;
}

// ---------- agg: one wave per (node, j); rel = rbase+j; nodes [c0, c0+cn) ----------
__global__ __launch_bounds__(256) void k_agg(const float* __restrict__ x,
                                             const int* __restrict__ rowptr,
                                             const int* __restrict__ esrc,
                                             float* __restrict__ out, int rbase, int c0, int cn) {
    int wid = blockIdx.x * 4 + (threadIdx.x >> 6);
    int lane = threadIdx.x & 63;
    int local = wid >> 1, j = wid & 1;
    if (local >= cn) return;
    int n = c0 + local;
    int s = (rbase + j) * NN + n;
    int beg = (s == 0) ? 0 : rowptr[s - 1];
    int end = rowptr[s];
    float ax = 0.f, ay = 0.f;
    int jj = beg;
    for (; jj + 4 <= end; jj += 4) {   // 4 row-loads in flight
        int s0 = esrc[jj], s1 = esrc[jj + 1], s2 = esrc[jj + 2], s3 = esrc[jj + 3];
        float2 v0 = ((const float2*)(x + (size_t)s0 * 128))[lane];
        float2 v1 = ((const float2*)(x + (size_t)s1 * 128))[lane];
        float2 v2 = ((const float2*)(x + (size_t)s2 * 128))[lane];
        float2 v3 = ((const float2*)(x + (size_t)s3 * 128))[lane];
        ax += (v0.x + v1.x) + (v2.x + v3.x);
        ay += (v0.y + v1.y) + (v2.y + v3.y);
    }
    for (; jj < end; ++jj) {
        float2 v = ((const float2*)(x + (size_t)esrc[jj] * 128))[lane];
        ax += v.x;
        ay += v.y;
    }
    ((float2*)&out[(size_t)local * 256 + j * 128])[lane] = make_float2(ax, ay);
}

// ---------- tiled GEMM: 128x128 out tile/block, Kc=32 LDS chunks, 8x8 micro-tile ----------
// MODE 0: out = acc   MODE 1: out += acc   MODE 2: out = relu(out + acc + bias)
template <int KEXT, int MODE>
__global__ __launch_bounds__(256, 3) void k_gemm(const float* __restrict__ A, int astride,
                                                 int c0, int crows,
                                                 const float* __restrict__ Wp,  // [KEXT][128]
                                                 const float* __restrict__ bias,
                                                 float* __restrict__ out) {
    __shared__ float Als[32][132];  // k-major
    __shared__ float Wls[32][132];
    const int t = threadIdx.x;
    const int tx = t & 15, ty = t >> 4;
    const int lrow0 = blockIdx.x * 128;

    float acc[2][2][4][4];
#pragma unroll
    for (int bi = 0; bi < 2; ++bi)
#pragma unroll
        for (int bj = 0; bj < 2; ++bj)
#pragma unroll
            for (int i = 0; i < 4; ++i)
#pragma unroll
                for (int j = 0; j < 4; ++j) acc[bi][bj][i][j] = 0.f;

#pragma unroll 1
    for (int kc = 0; kc < KEXT; kc += 32) {
        __syncthreads();
        // stage A chunk [128 rows x 32 k], transposed into Als[k][row]
#pragma unroll
        for (int r_ = 0; r_ < 4; ++r_) {
            int f4i = r_ * 256 + t;
            int row = f4i >> 3, kq = f4i & 7;
            float4 v = make_float4(0.f, 0.f, 0.f, 0.f);
            if (lrow0 + row < crows)
                v = *(const float4*)&A[(size_t)(lrow0 + row) * astride + kc + kq * 4];
            Als[kq * 4 + 0][row] = v.x;
            Als[kq * 4 + 1][row] = v.y;
            Als[kq * 4 + 2][row] = v.z;
            Als[kq * 4 + 3][row] = v.w;
        }
        // stage W chunk [32 k x 128 cols]
#pragma unroll
        for (int r_ = 0; r_ < 4; ++r_) {
            int f4i = r_ * 256 + t;
            int wrow = f4i >> 5, wc = (f4i & 31) * 4;
            *(float4*)&Wls[wrow][wc] = *(const float4*)&Wp[(size_t)(kc + wrow) * 128 + wc];
        }
        __syncthreads();
#pragma unroll 8
        for (int kk = 0; kk < 32; ++kk) {
            float4 a0 = *(const float4*)&Als[kk][ty * 4];
            float4 a1 = *(const float4*)&Als[kk][64 + ty * 4];
            float4 w0 = *(const float4*)&Wls[kk][tx * 4];
            float4 w1 = *(const float4*)&Wls[kk][64 + tx * 4];
            float ar[2][4] = {{a0.x, a0.y, a0.z, a0.w}, {a1.x, a1.y, a1.z, a1.w}};
            float wr[2][4] = {{w0.x, w0.y, w0.z, w0.w}, {w1.x, w1.y, w1.z, w1.w}};
#pragma unroll
            for (int bi = 0; bi < 2; ++bi)
#pragma unroll
                for (int bj = 0; bj < 2; ++bj)
#pragma unroll
                    for (int i = 0; i < 4; ++i)
#pragma unroll
                        for (int j = 0; j < 4; ++j)
                            acc[bi][bj][i][j] += ar[bi][i] * wr[bj][j];
        }
    }
    // epilogue
#pragma unroll
    for (int bi = 0; bi < 2; ++bi)
#pragma unroll
        for (int i = 0; i < 4; ++i) {
            int lrow = lrow0 + bi * 64 + ty * 4 + i;
            if (lrow < crows) {
#pragma unroll
                for (int bj = 0; bj < 2; ++bj) {
                    int col = bj * 64 + tx * 4;
                    size_t off = (size_t)(c0 + lrow) * 128 + col;
                    float4 v = make_float4(acc[bi][bj][i][0], acc[bi][bj][i][1],
                                           acc[bi][bj][i][2], acc[bi][bj][i][3]);
                    if (MODE == 0) {
                        *(float4*)&out[off] = v;
                    } else if (MODE == 1) {
                        float4 p = *(const float4*)&out[off];
                        v.x += p.x; v.y += p.y; v.z += p.z; v.w += p.w;
                        *(float4*)&out[off] = v;
                    } else {
                        float4 p = *(const float4*)&out[off];
                        float4 bb = *(const float4*)&bias[col];
                        v.x = frelu(v.x + p.x + bb.x);
                        v.y = frelu(v.y + p.y + bb.y);
                        v.z = frelu(v.z + p.z + bb.z);
                        v.w = frelu(v.w + p.w + bb.w);
                        *(float4*)&out[off] = v;
                    }
                }
            }
        }
}

// ---------- column-wise sum/max over final x ----------
__global__ void k_reduce(const float* __restrict__ x, float* __restrict__ gsum,
                         unsigned* __restrict__ gmax) {
    int c = threadIdx.x & 127;
    int half = threadIdx.x >> 7;
    int rbeg = blockIdx.x * 512 + half;
    int rend = min(blockIdx.x * 512 + 512, NN);
    float s = 0.f, m = 0.f;  // post-relu values >= 0
    for (int r = rbeg; r < rend; r += 2) {
        float v = x[(size_t)r * 128 + c];
        s += v;
        m = fmaxf(m, v);
    }
    atomicAdd(&gsum[c], s);
    atomicMax(&gmax[c], __float_as_uint(m));  // valid: all values >= 0
}

// ---------- heads (single block) ----------
__global__ void k_head(const float* __restrict__ x, const float* __restrict__ gsum,
                       const unsigned* __restrict__ gmaxu, const int* __restrict__ anchor_idx,
                       const float* __restrict__ numeric, const float* __restrict__ boolean_,
                       const int* __restrict__ cats, const float* __restrict__ ce0,
                       const float* __restrict__ ce1, const float* __restrict__ ce2,
                       const float* __restrict__ featW, const float* __restrict__ featb,
                       const float* __restrict__ binW1, const float* __restrict__ binb1,
                       const float* __restrict__ binW2, const float* __restrict__ binb2,
                       const float* __restrict__ mcW1, const float* __restrict__ mcb1,
                       const float* __restrict__ mcW2, const float* __restrict__ mcb2,
                       float* __restrict__ out) {
    __shared__ float comb[432];
    __shared__ float feat[72];
    __shared__ float hb[4][64];
    int t = threadIdx.x;
    int anchor = anchor_idx[0];
    if (t < 128) {
        comb[t] = x[(size_t)anchor * 128 + t];
        comb[128 + t] = gsum[t] * (1.0f / (float)NN);
        comb[256 + t] = __uint_as_float(gmaxu[t]);
    }
    if (t < 32) feat[t] = numeric[t];
    else if (t < 48) feat[t] = boolean_[t - 32];
    else if (t < 56) feat[t] = ce0[cats[0] * 8 + (t - 48)];
    else if (t < 64) feat[t] = ce1[cats[1] * 8 + (t - 56)];
    else if (t < 72) feat[t] = ce2[cats[2] * 8 + (t - 64)];
    __syncthreads();
    if (t < 48) {
        float s = featb[t];
        for (int c = 0; c < 72; ++c) s += featW[t * 72 + c] * feat[c];
        comb[384 + t] = frelu(s);
    }
    __syncthreads();
    {
        int head = t >> 6, u = t & 63;
        const float* W;
        float s;
        if (head < 3) {
            W = binW1 + ((size_t)head * 64 + u) * 432;
            s = binb1[head * 64 + u];
        } else {
            W = mcW1 + (size_t)u * 432;
            s = mcb1[u];
        }
        for (int c = 0; c < 432; ++c) s += W[c] * comb[c];
        hb[head][u] = frelu(s);
    }
    __syncthreads();
    if (t < 3) {
        float s = binb2[t];
        for (int u = 0; u < 64; ++u) s += binW2[t * 64 + u] * hb[t][u];
        out[t] = s;
    } else if (t < 7) {
        int k = t - 3;
        float s = mcb2[k];
        for (int u = 0; u < 64; ++u) s += mcW2[k * 64 + u] * hb[3][u];
        out[3 + k] = s;
    }
}

extern "C" void kernel_launch(void* const* d_in, const int* in_sizes, int n_in,
                              void* d_out, int out_size, void* d_ws, size_t ws_size,
                              hipStream_t stream) {
    const int* ntype = (const int*)d_in[0];
    const int* eidx = (const int*)d_in[1];
    const int* etype = (const int*)d_in[2];
    const int* cats = (const int*)d_in[3];
    const int* anchor = (const int*)d_in[4];
    const float* numeric = (const float*)d_in[5];
    const float* boolean_ = (const float*)d_in[6];
    const float* nemb = (const float*)d_in[7];
    const float* selfW = (const float*)d_in[8];
    const float* selfb = (const float*)d_in[9];
    const float* relW = (const float*)d_in[10];
    const float* ce0 = (const float*)d_in[11];
    const float* ce1 = (const float*)d_in[12];
    const float* ce2 = (const float*)d_in[13];
    const float* featW = (const float*)d_in[14];
    const float* featb = (const float*)d_in[15];
    const float* binW1 = (const float*)d_in[16];
    const float* binb1 = (const float*)d_in[17];
    const float* binW2 = (const float*)d_in[18];
    const float* binb2 = (const float*)d_in[19];
    const float* mcW1 = (const float*)d_in[20];
    const float* mcb1 = (const float*)d_in[21];
    const float* mcW2 = (const float*)d_in[22];
    const float* mcb2 = (const float*)d_in[23];
    float* out = (float*)d_out;

    char* ws = (char*)d_ws;
    size_t off = 0;
    auto alloc = [&](size_t bytes) -> void* {
        void* pp = ws + off;
        off += (bytes + 255) & ~(size_t)255;
        return pp;
    };
    // fixed footprint (~114 MiB)
    float* bufA = (float*)alloc((size_t)NN * 128 * 4);
    float* bufB = (float*)alloc((size_t)NN * 128 * 4);
    int* rowptr = (int*)alloc((size_t)NSEG * 4);
    int* partials = (int*)alloc(4096);
    int* esrc = (int*)alloc((size_t)EE * 4);
    float* Wp = (float*)alloc((size_t)2 * KTOT * 128 * 4);
    float* gsum = (float*)alloc(512);
    unsigned* gmax = (unsigned*)alloc(512);
    // adaptive chunk buffer: 2 relation slots (256 floats) per node
    size_t avail = (ws_size > off) ? (ws_size - off) : 0;
    int chunk = (int)((avail / (256 * 4)));
    if (chunk > NN) chunk = NN;
    if (chunk < 128) chunk = 128;  // ws_size below ~115MiB is unrecoverable anyway
    float* chunkbuf = (float*)(ws + off);
    (void)in_sizes; (void)n_in; (void)out_size;

    hipMemsetAsync(rowptr, 0, (size_t)NSEG * 4, stream);
    hipMemsetAsync(gsum, 0, 512, stream);
    hipMemsetAsync(gmax, 0, 512, stream);

    k_gather_x<<<NN * 32 / 256, 256, 0, stream>>>(ntype, nemb, bufA);
    k_count<<<2048, 256, 0, stream>>>(eidx, etype, rowptr);
    int nb1 = (NSEG + 1023) / 1024;
    k_scan1<<<nb1, 256, 0, stream>>>(rowptr, partials, NSEG);
    k_scan2<<<1, 1024, 0, stream>>>(partials, nb1);
    k_scan3<<<(NSEG + 255) / 256, 256, 0, stream>>>(rowptr, partials, NSEG);
    k_scatter<<<2048, 256, 0, stream>>>(eidx, etype, rowptr, esrc);
    k_prepW<<<2 * KTOT * 128 / 256, 256, 0, stream>>>(relW, selfW, Wp);

    for (int l = 0; l < 2; ++l) {
        const float* xin = (l == 0) ? bufA : bufB;
        float* xout = (l == 0) ? bufB : bufA;
        const float* Wl = Wp + (size_t)l * KTOT * 128;
        const float* bl = selfb + l * 128;
        for (int p = 0; p < 4; ++p) {
            for (int c0 = 0; c0 < NN; c0 += chunk) {
                int cn = (NN - c0 < chunk) ? (NN - c0) : chunk;
                k_agg<<<(2 * cn + 3) / 4, 256, 0, stream>>>(xin, rowptr, esrc, chunkbuf,
                                                            2 * p, c0, cn);
                int gb = (cn + 127) / 128;
                if (p == 0)
                    k_gemm<256, 0><<<gb, 256, 0, stream>>>(chunkbuf, 256, c0, cn,
                                                           Wl + (size_t)p * 256 * 128, bl, xout);
                else
                    k_gemm<256, 1><<<gb, 256, 0, stream>>>(chunkbuf, 256, c0, cn,
                                                           Wl + (size_t)p * 256 * 128, bl, xout);
            }
        }
        // self term + bias + relu (KEXT=128, A = xin)
        k_gemm<128, 2><<<(NN + 127) / 128, 256, 0, stream>>>(xin, 128, 0, NN,
                                                             Wl + (size_t)1024 * 128, bl, xout);
    }

    k_reduce<<<(NN + 511) / 512, 256, 0, stream>>>(bufA, gsum, gmax);
    k_head<<<1, 256, 0, stream>>>(bufA, gsum, gmax, anchor, numeric, boolean_, cats, ce0, ce1,
                                  ce2, featW, featb, binW1, binb1, binW2, binb2, mcW1, mcb1,
                                  mcW2, mcb2, out);
}

// Round 6
// 1890.154 us; speedup vs baseline: 4.4928x; 1.1757x over previous
//
#include <hip/hip_runtime.h>
#include <hip/hip_bf16.h>

// R6 = R5 resubmitted unchanged (R5 failed on infra: GPUAcquisitionTimeout,
// kernel never executed). Audit found no defect; see round notes.

#define NN 100000
#define EE 3200000

typedef __attribute__((ext_vector_type(8))) short bf16x8;
typedef __attribute__((ext_vector_type(4))) float f32x4;

static __device__ __forceinline__ float frelu(float v) { return v > 0.f ? v : 0.f; }

// round-to-nearest-even f32 -> bf16 bits
static __device__ __forceinline__ unsigned short f2bf(float f) {
    unsigned b = __float_as_uint(f);
    return (unsigned short)((b + 0x7fffu + ((b >> 16) & 1u)) >> 16);
}
static __device__ __forceinline__ unsigned packbf(float lo, float hi) {
    return (unsigned)f2bf(lo) | ((unsigned)f2bf(hi) << 16);
}
static __device__ __forceinline__ float bflo(unsigned u) { return __uint_as_float(u << 16); }
static __device__ __forceinline__ float bfhi(unsigned u) { return __uint_as_float(u & 0xffff0000u); }
static __device__ __forceinline__ float bf2f(unsigned short u) {
    return __uint_as_float(((unsigned)u) << 16);
}

// ---------- x0 = bf16(node_emb[node_type_ids]) ----------
__global__ void k_gather_xb(const int* __restrict__ ntype, const float* __restrict__ nemb,
                            unsigned* __restrict__ xb) {
    int i = blockIdx.x * 256 + threadIdx.x;  // exactly N*64 threads; q covers dims 2q,2q+1
    int n = i >> 6, q = i & 63;
    int tt = ntype[n];
    float2 v = ((const float2*)(nemb + (size_t)tt * 128))[q];
    xb[(size_t)n * 64 + q] = packbf(v.x, v.y);
}

// ---------- CSR build keyed by tgt ONLY (N segments, L2-resident atomics) ----------
__global__ void k_count(const int* __restrict__ eidx, int* __restrict__ rowptr) {
    for (int e = blockIdx.x * blockDim.x + threadIdx.x; e < EE; e += gridDim.x * blockDim.x) {
        int2 p = ((const int2*)eidx)[e];
        atomicAdd(&rowptr[p.y], 1);
    }
}

__global__ void k_scan1(int* data, int* partials, int nseg) {
    __shared__ int sd[256];
    int t = threadIdx.x;
    int base = blockIdx.x * 1024 + t * 4;
    int v[4];
#pragma unroll
    for (int k = 0; k < 4; ++k) v[k] = (base + k < nseg) ? data[base + k] : 0;
    int tsum = v[0] + v[1] + v[2] + v[3];
    sd[t] = tsum;
    __syncthreads();
    for (int off = 1; off < 256; off <<= 1) {
        int add = (t >= off) ? sd[t - off] : 0;
        __syncthreads();
        sd[t] += add;
        __syncthreads();
    }
    int run = sd[t] - tsum;
#pragma unroll
    for (int k = 0; k < 4; ++k) {
        if (base + k < nseg) data[base + k] = run;
        run += v[k];
    }
    if (t == 255) partials[blockIdx.x] = sd[255];
}

__global__ void k_scan2(int* partials, int nb) {
    __shared__ int sd[1024];
    int t = threadIdx.x;
    int v = (t < nb) ? partials[t] : 0;
    sd[t] = v;
    __syncthreads();
    for (int off = 1; off < 1024; off <<= 1) {
        int add = (t >= off) ? sd[t - off] : 0;
        __syncthreads();
        sd[t] += add;
        __syncthreads();
    }
    if (t < nb) partials[t] = sd[t] - v;
}

__global__ void k_scan3(int* rowptr, const int* __restrict__ partials, int nseg) {
    int i = blockIdx.x * 256 + threadIdx.x;
    if (i < nseg) rowptr[i] += partials[i >> 10];
}

// scatter packed (src<<3)|rel; rowptr becomes inclusive segment ENDS
__global__ void k_scatter(const int* __restrict__ eidx, const int* __restrict__ etype,
                          int* rowptr, int* __restrict__ pk) {
    for (int e = blockIdx.x * blockDim.x + threadIdx.x; e < EE; e += gridDim.x * blockDim.x) {
        int2 p = ((const int2*)eidx)[e];
        int rel = etype[e];
        int pos = atomicAdd(&rowptr[p.y], 1);
        pk[pos] = (p.x << 3) | rel;
    }
}

// ---------- Wb[l][d][k] bf16: k<1024 -> relW[l][k>>7][d][k&127]; else selfW[l][d][k-1024]
__global__ void k_prepWb(const float* __restrict__ relW, const float* __restrict__ selfW,
                         unsigned short* __restrict__ Wb) {
    int idx = blockIdx.x * 256 + threadIdx.x;  // 2*128*1152 threads
    int k = idx % 1152;
    int d = (idx / 1152) & 127;
    int l = idx / (1152 * 128);
    float v;
    if (k < 1024)
        v = relW[((((size_t)l * 8) + (k >> 7)) * 128 + d) * 128 + (k & 127)];
    else
        v = selfW[((size_t)l * 128 + d) * 128 + (k - 1024)];
    Wb[idx] = f2bf(v);
}

// ---------- agg: one wave per node, all 8 relations accumulated at once ----------
static __device__ __forceinline__ void addpk(float acc[8][2], int kk, unsigned u) {
    float lo = bflo(u), hi = bfhi(u);
    switch (kk & 7) {  // wave-uniform branch (kk broadcast-loaded)
        case 0: acc[0][0] += lo; acc[0][1] += hi; break;
        case 1: acc[1][0] += lo; acc[1][1] += hi; break;
        case 2: acc[2][0] += lo; acc[2][1] += hi; break;
        case 3: acc[3][0] += lo; acc[3][1] += hi; break;
        case 4: acc[4][0] += lo; acc[4][1] += hi; break;
        case 5: acc[5][0] += lo; acc[5][1] += hi; break;
        case 6: acc[6][0] += lo; acc[6][1] += hi; break;
        case 7: acc[7][0] += lo; acc[7][1] += hi; break;
    }
}

__global__ __launch_bounds__(256) void k_agg8(const unsigned* __restrict__ xb,
                                              const int* __restrict__ rowptr,
                                              const int* __restrict__ pk,
                                              unsigned* __restrict__ aggb, int c0, int cn) {
    int local = blockIdx.x * 4 + (threadIdx.x >> 6);
    int lane = threadIdx.x & 63;
    if (local >= cn) return;
    int n = c0 + local;
    int beg = n ? rowptr[n - 1] : 0;
    int end = rowptr[n];
    float acc[8][2];
#pragma unroll
    for (int r = 0; r < 8; ++r) { acc[r][0] = 0.f; acc[r][1] = 0.f; }
    int j = beg;
    for (; j + 4 <= end; j += 4) {  // 4 row-loads in flight
        int k0 = pk[j], k1 = pk[j + 1], k2 = pk[j + 2], k3 = pk[j + 3];
        unsigned u0 = xb[(size_t)(k0 >> 3) * 64 + lane];
        unsigned u1 = xb[(size_t)(k1 >> 3) * 64 + lane];
        unsigned u2 = xb[(size_t)(k2 >> 3) * 64 + lane];
        unsigned u3 = xb[(size_t)(k3 >> 3) * 64 + lane];
        addpk(acc, k0, u0);
        addpk(acc, k1, u1);
        addpk(acc, k2, u2);
        addpk(acc, k3, u3);
    }
    for (; j < end; ++j) {
        int kk = pk[j];
        unsigned u = xb[(size_t)(kk >> 3) * 64 + lane];
        addpk(acc, kk, u);
    }
#pragma unroll
    for (int r = 0; r < 8; ++r)
        aggb[(size_t)local * 512 + r * 64 + lane] = packbf(acc[r][0], acc[r][1]);
}

// ---------- MFMA GEMM: out[n][d] = relu( sum_k A[n][k] Wb[d][k] + b[d] ), K=1152 ----------
// A = [aggb local rows, K=1024 bf16] ++ [xb_in global rows, K=128 bf16]
// block = 256 thr = 4 waves; wave = 16 rows x 128 cols; 8 col-frags x 36 k-steps of 32
__global__ __launch_bounds__(256) void k_mm(const unsigned short* __restrict__ aggb,
                                            const unsigned short* __restrict__ xbin,
                                            const unsigned short* __restrict__ Wb,  // [128][1152]
                                            const float* __restrict__ bias,
                                            unsigned short* __restrict__ xbout,
                                            int c0, int cn) {
    const int wv = threadIdx.x >> 6, lane = threadIdx.x & 63;
    const int r_in = lane & 15, kq = lane >> 4;
    const int lm0 = blockIdx.x * 64 + wv * 16;

    f32x4 acc[8];
#pragma unroll
    for (int cf = 0; cf < 8; ++cf) acc[cf] = (f32x4){0.f, 0.f, 0.f, 0.f};

    int la = lm0 + r_in;
    if (la >= cn) la = cn - 1;                      // clamp (stores masked below)
    const unsigned short* Arow = aggb + (size_t)la * 1024 + kq * 8;
    const unsigned short* Xrow = xbin + (size_t)(c0 + la) * 128 + kq * 8;
    const unsigned short* Brow = Wb + (size_t)r_in * 1152 + kq * 8;

#pragma unroll 1
    for (int ks = 0; ks < 36; ++ks) {
        const unsigned short* ap = (ks < 32) ? (Arow + ks * 32) : (Xrow + (ks - 32) * 32);
        bf16x8 a = *(const bf16x8*)ap;
#pragma unroll
        for (int cf = 0; cf < 8; ++cf) {
            bf16x8 b = *(const bf16x8*)(Brow + (size_t)cf * 16 * 1152 + ks * 32);
            acc[cf] = __builtin_amdgcn_mfma_f32_16x16x32_bf16(a, b, acc[cf], 0, 0, 0);
        }
    }
    // epilogue: bias + relu -> bf16;  D: col = cf*16 + (lane&15), row = kq*4 + reg
    int grb = c0 + lm0 + kq * 4;
    int glim = c0 + cn;
#pragma unroll
    for (int cf = 0; cf < 8; ++cf) {
        int d = cf * 16 + r_in;
        float bv = bias[d];
#pragma unroll
        for (int reg = 0; reg < 4; ++reg) {
            int gr = grb + reg;
            if (gr < glim)
                xbout[(size_t)gr * 128 + d] = f2bf(frelu(acc[cf][reg] + bv));
        }
    }
}

// ---------- column-wise sum/max over final bf16 x ----------
__global__ void k_reduce(const unsigned short* __restrict__ xb, float* __restrict__ gsum,
                         unsigned* __restrict__ gmax) {
    int c = threadIdx.x & 127;
    int half = threadIdx.x >> 7;
    int rbeg = blockIdx.x * 512 + half;
    int rend = min(blockIdx.x * 512 + 512, NN);
    float s = 0.f, m = 0.f;  // post-relu >= 0
    for (int r = rbeg; r < rend; r += 2) {
        float v = bf2f(xb[(size_t)r * 128 + c]);
        s += v;
        m = fmaxf(m, v);
    }
    atomicAdd(&gsum[c], s);
    atomicMax(&gmax[c], __float_as_uint(m));
}

// ---------- heads (single block), fp32 exact on fp32 head weights ----------
__global__ void k_head(const unsigned short* __restrict__ x, const float* __restrict__ gsum,
                       const unsigned* __restrict__ gmaxu, const int* __restrict__ anchor_idx,
                       const float* __restrict__ numeric, const float* __restrict__ boolean_,
                       const int* __restrict__ cats, const float* __restrict__ ce0,
                       const float* __restrict__ ce1, const float* __restrict__ ce2,
                       const float* __restrict__ featW, const float* __restrict__ featb,
                       const float* __restrict__ binW1, const float* __restrict__ binb1,
                       const float* __restrict__ binW2, const float* __restrict__ binb2,
                       const float* __restrict__ mcW1, const float* __restrict__ mcb1,
                       const float* __restrict__ mcW2, const float* __restrict__ mcb2,
                       float* __restrict__ out) {
    __shared__ float comb[432];
    __shared__ float feat[72];
    __shared__ float hb[4][64];
    int t = threadIdx.x;
    int anchor = anchor_idx[0];
    if (t < 128) {
        comb[t] = bf2f(x[(size_t)anchor * 128 + t]);
        comb[128 + t] = gsum[t] * (1.0f / (float)NN);
        comb[256 + t] = __uint_as_float(gmaxu[t]);
    }
    if (t < 32) feat[t] = numeric[t];
    else if (t < 48) feat[t] = boolean_[t - 32];
    else if (t < 56) feat[t] = ce0[cats[0] * 8 + (t - 48)];
    else if (t < 64) feat[t] = ce1[cats[1] * 8 + (t - 56)];
    else if (t < 72) feat[t] = ce2[cats[2] * 8 + (t - 64)];
    __syncthreads();
    if (t < 48) {
        float s = featb[t];
        for (int c = 0; c < 72; ++c) s += featW[t * 72 + c] * feat[c];
        comb[384 + t] = frelu(s);
    }
    __syncthreads();
    {
        int head = t >> 6, u = t & 63;
        const float* W;
        float s;
        if (head < 3) {
            W = binW1 + ((size_t)head * 64 + u) * 432;
            s = binb1[head * 64 + u];
        } else {
            W = mcW1 + (size_t)u * 432;
            s = mcb1[u];
        }
        for (int c = 0; c < 432; ++c) s += W[c] * comb[c];
        hb[head][u] = frelu(s);
    }
    __syncthreads();
    if (t < 3) {
        float s = binb2[t];
        for (int u = 0; u < 64; ++u) s += binW2[t * 64 + u] * hb[t][u];
        out[t] = s;
    } else if (t < 7) {
        int k = t - 3;
        float s = mcb2[k];
        for (int u = 0; u < 64; ++u) s += mcW2[k * 64 + u] * hb[3][u];
        out[3 + k] = s;
    }
}

extern "C" void kernel_launch(void* const* d_in, const int* in_sizes, int n_in,
                              void* d_out, int out_size, void* d_ws, size_t ws_size,
                              hipStream_t stream) {
    const int* ntype = (const int*)d_in[0];
    const int* eidx = (const int*)d_in[1];
    const int* etype = (const int*)d_in[2];
    const int* cats = (const int*)d_in[3];
    const int* anchor = (const int*)d_in[4];
    const float* numeric = (const float*)d_in[5];
    const float* boolean_ = (const float*)d_in[6];
    const float* nemb = (const float*)d_in[7];
    const float* selfW = (const float*)d_in[8];
    const float* selfb = (const float*)d_in[9];
    const float* relW = (const float*)d_in[10];
    const float* ce0 = (const float*)d_in[11];
    const float* ce1 = (const float*)d_in[12];
    const float* ce2 = (const float*)d_in[13];
    const float* featW = (const float*)d_in[14];
    const float* featb = (const float*)d_in[15];
    const float* binW1 = (const float*)d_in[16];
    const float* binb1 = (const float*)d_in[17];
    const float* binW2 = (const float*)d_in[18];
    const float* binb2 = (const float*)d_in[19];
    const float* mcW1 = (const float*)d_in[20];
    const float* mcb1 = (const float*)d_in[21];
    const float* mcW2 = (const float*)d_in[22];
    const float* mcb2 = (const float*)d_in[23];
    float* out = (float*)d_out;

    char* ws = (char*)d_ws;
    size_t off = 0;
    auto alloc = [&](size_t bytes) -> void* {
        void* pp = ws + off;
        off += (bytes + 255) & ~(size_t)255;
        return pp;
    };
    // fixed footprint ~65 MiB
    unsigned* xbA = (unsigned*)alloc((size_t)NN * 64 * 4);  // bf16 x, packed pairs
    unsigned* xbB = (unsigned*)alloc((size_t)NN * 64 * 4);
    int* rowptr = (int*)alloc((size_t)NN * 4);
    int* partials = (int*)alloc(4096);
    int* pkbuf = (int*)alloc((size_t)EE * 4);
    unsigned short* Wb = (unsigned short*)alloc((size_t)2 * 128 * 1152 * 2);
    float* gsum = (float*)alloc(512);
    unsigned* gmax = (unsigned*)alloc(512);
    // adaptive agg chunk: 2048 B per node (8 rel x 128 bf16)
    size_t avail = (ws_size > off) ? (ws_size - off) : 0;
    int chunk = (int)(avail / 2048);
    chunk &= ~63;                 // multiple of 64 for k_mm blocks
    if (chunk > NN) chunk = NN;
    if (chunk < 64) chunk = 64;   // ws below ~66 MiB is unrecoverable anyway
    unsigned* aggb = (unsigned*)(ws + off);
    (void)in_sizes; (void)n_in; (void)out_size;

    hipMemsetAsync(rowptr, 0, (size_t)NN * 4, stream);
    hipMemsetAsync(gsum, 0, 512, stream);
    hipMemsetAsync(gmax, 0, 512, stream);

    k_gather_xb<<<NN * 64 / 256, 256, 0, stream>>>(ntype, nemb, xbA);
    k_count<<<2048, 256, 0, stream>>>(eidx, rowptr);
    int nb1 = (NN + 1023) / 1024;  // 98 <= 1024
    k_scan1<<<nb1, 256, 0, stream>>>(rowptr, partials, NN);
    k_scan2<<<1, 1024, 0, stream>>>(partials, nb1);
    k_scan3<<<(NN + 255) / 256, 256, 0, stream>>>(rowptr, partials, NN);
    k_scatter<<<2048, 256, 0, stream>>>(eidx, etype, rowptr, pkbuf);
    k_prepWb<<<2 * 128 * 1152 / 256, 256, 0, stream>>>(relW, selfW, Wb);

    for (int l = 0; l < 2; ++l) {
        const unsigned* xin = l ? xbB : xbA;
        unsigned short* xout = (unsigned short*)(l ? xbA : xbB);
        const unsigned short* Wl = Wb + (size_t)l * 128 * 1152;
        const float* bl = selfb + l * 128;
        for (int c0 = 0; c0 < NN; c0 += chunk) {
            int cn = (NN - c0 < chunk) ? (NN - c0) : chunk;
            k_agg8<<<(cn + 3) / 4, 256, 0, stream>>>(xin, rowptr, pkbuf, aggb, c0, cn);
            k_mm<<<(cn + 63) / 64, 256, 0, stream>>>((const unsigned short*)aggb,
                                                     (const unsigned short*)xin, Wl, bl,
                                                     xout, c0, cn);
        }
    }

    // final x is in xbA (layer 1 wrote to it)
    k_reduce<<<(NN + 511) / 512, 256, 0, stream>>>((const unsigned short*)xbA, gsum, gmax);
    k_head<<<1, 256, 0, stream>>>((const unsigned short*)xbA, gsum, gmax, anchor, numeric,
                                  boolean_, cats, ce0, ce1, ce2, featW, featb, binW1, binb1,
                                  binW2, binb2, mcW1, mcb1, mcW2, mcb2, out);
}

// Round 7
// 1829.862 us; speedup vs baseline: 4.6408x; 1.0329x over previous
//
#include <hip/hip_runtime.h>
#include <hip/hip_bf16.h>

// R7: fuse k_agg8 + k_mm into k_fused (kills aggb round-trip: 205 MB write
// measured as 791 MB HBM-level WRITE + 205 MB re-read, per layer).
// Gather: wave-per-node fp32 acc (ILP 8) -> swizzled 32KB LDS bf16 tile.
// MFMA: R6's validated 16x16x32 structure, K=1152 (1024 LDS + 128 self from global).

#define NN 100000
#define EE 3200000
#define TN 16   // nodes per block; NN = 16 * 6250 exactly

typedef __attribute__((ext_vector_type(8))) short bf16x8;
typedef __attribute__((ext_vector_type(4))) float f32x4;

static __device__ __forceinline__ float frelu(float v) { return v > 0.f ? v : 0.f; }

// round-to-nearest-even f32 -> bf16 bits
static __device__ __forceinline__ unsigned short f2bf(float f) {
    unsigned b = __float_as_uint(f);
    return (unsigned short)((b + 0x7fffu + ((b >> 16) & 1u)) >> 16);
}
static __device__ __forceinline__ unsigned packbf(float lo, float hi) {
    return (unsigned)f2bf(lo) | ((unsigned)f2bf(hi) << 16);
}
static __device__ __forceinline__ float bflo(unsigned u) { return __uint_as_float(u << 16); }
static __device__ __forceinline__ float bfhi(unsigned u) { return __uint_as_float(u & 0xffff0000u); }
static __device__ __forceinline__ float bf2f(unsigned short u) {
    return __uint_as_float(((unsigned)u) << 16);
}

// ---------- x0 = bf16(node_emb[node_type_ids]) ----------
__global__ void k_gather_xb(const int* __restrict__ ntype, const float* __restrict__ nemb,
                            unsigned* __restrict__ xb) {
    int i = blockIdx.x * 256 + threadIdx.x;  // exactly N*64 threads; q covers dims 2q,2q+1
    int n = i >> 6, q = i & 63;
    int tt = ntype[n];
    float2 v = ((const float2*)(nemb + (size_t)tt * 128))[q];
    xb[(size_t)n * 64 + q] = packbf(v.x, v.y);
}

// ---------- CSR build keyed by tgt ONLY (N segments, L2-resident atomics) ----------
__global__ void k_count(const int* __restrict__ eidx, int* __restrict__ rowptr) {
    for (int e = blockIdx.x * blockDim.x + threadIdx.x; e < EE; e += gridDim.x * blockDim.x) {
        int2 p = ((const int2*)eidx)[e];
        atomicAdd(&rowptr[p.y], 1);
    }
}

__global__ void k_scan1(int* data, int* partials, int nseg) {
    __shared__ int sd[256];
    int t = threadIdx.x;
    int base = blockIdx.x * 1024 + t * 4;
    int v[4];
#pragma unroll
    for (int k = 0; k < 4; ++k) v[k] = (base + k < nseg) ? data[base + k] : 0;
    int tsum = v[0] + v[1] + v[2] + v[3];
    sd[t] = tsum;
    __syncthreads();
    for (int off = 1; off < 256; off <<= 1) {
        int add = (t >= off) ? sd[t - off] : 0;
        __syncthreads();
        sd[t] += add;
        __syncthreads();
    }
    int run = sd[t] - tsum;
#pragma unroll
    for (int k = 0; k < 4; ++k) {
        if (base + k < nseg) data[base + k] = run;
        run += v[k];
    }
    if (t == 255) partials[blockIdx.x] = sd[255];
}

__global__ void k_scan2(int* partials, int nb) {
    __shared__ int sd[1024];
    int t = threadIdx.x;
    int v = (t < nb) ? partials[t] : 0;
    sd[t] = v;
    __syncthreads();
    for (int off = 1; off < 1024; off <<= 1) {
        int add = (t >= off) ? sd[t - off] : 0;
        __syncthreads();
        sd[t] += add;
        __syncthreads();
    }
    if (t < nb) partials[t] = sd[t] - v;
}

__global__ void k_scan3(int* rowptr, const int* __restrict__ partials, int nseg) {
    int i = blockIdx.x * 256 + threadIdx.x;
    if (i < nseg) rowptr[i] += partials[i >> 10];
}

// scatter packed (src<<3)|rel; rowptr becomes inclusive segment ENDS
__global__ void k_scatter(const int* __restrict__ eidx, const int* __restrict__ etype,
                          int* rowptr, int* __restrict__ pk) {
    for (int e = blockIdx.x * blockDim.x + threadIdx.x; e < EE; e += gridDim.x * blockDim.x) {
        int2 p = ((const int2*)eidx)[e];
        int rel = etype[e];
        int pos = atomicAdd(&rowptr[p.y], 1);
        pk[pos] = (p.x << 3) | rel;
    }
}

// ---------- Wb[l][d][k] bf16: k<1024 -> relW[l][k>>7][d][k&127]; else selfW[l][d][k-1024]
__global__ void k_prepWb(const float* __restrict__ relW, const float* __restrict__ selfW,
                         unsigned short* __restrict__ Wb) {
    int idx = blockIdx.x * 256 + threadIdx.x;  // 2*128*1152 threads
    int k = idx % 1152;
    int d = (idx / 1152) & 127;
    int l = idx / (1152 * 128);
    float v;
    if (k < 1024)
        v = relW[((((size_t)l * 8) + (k >> 7)) * 128 + d) * 128 + (k & 127)];
    else
        v = selfW[((size_t)l * 128 + d) * 128 + (k - 1024)];
    Wb[idx] = f2bf(v);
}

// ---------- fused: gather 16 nodes' 8-rel aggs into swizzled LDS, then MFMA ----------
static __device__ __forceinline__ void addpk(float acc[8][2], int kk, unsigned u) {
    float lo = bflo(u), hi = bfhi(u);
    switch (kk & 7) {  // wave-uniform branch (kk broadcast-loaded)
        case 0: acc[0][0] += lo; acc[0][1] += hi; break;
        case 1: acc[1][0] += lo; acc[1][1] += hi; break;
        case 2: acc[2][0] += lo; acc[2][1] += hi; break;
        case 3: acc[3][0] += lo; acc[3][1] += hi; break;
        case 4: acc[4][0] += lo; acc[4][1] += hi; break;
        case 5: acc[5][0] += lo; acc[5][1] += hi; break;
        case 6: acc[6][0] += lo; acc[6][1] += hi; break;
        case 7: acc[7][0] += lo; acc[7][1] += hi; break;
    }
}

__global__ __launch_bounds__(256) void k_fused(const unsigned* __restrict__ xb,
                                               const int* __restrict__ rowptr,
                                               const int* __restrict__ pk,
                                               const unsigned short* __restrict__ Wb,  // [128][1152]
                                               const float* __restrict__ bias,
                                               unsigned short* __restrict__ xbout) {
    // LDS tile: 16 rows x 1024 bf16 (k=0..1023), 16B-granule XOR swizzle (g ^= row&7)
    __shared__ unsigned smU[TN * 512];  // 32 KB
    const int wv = threadIdx.x >> 6, lane = threadIdx.x & 63;
    const int n0 = blockIdx.x * TN;

    // ---- gather phase: wave wv aggregates nodes i = wv*4 .. wv*4+3 ----
    for (int i = wv * 4; i < wv * 4 + 4; ++i) {
        int n = n0 + i;
        int beg = n ? rowptr[n - 1] : 0;
        int end = rowptr[n];
        float acc[8][2];
#pragma unroll
        for (int r = 0; r < 8; ++r) { acc[r][0] = 0.f; acc[r][1] = 0.f; }
        int j = beg;
        for (; j + 8 <= end; j += 8) {  // 8 row-loads in flight
            int kk[8];
            unsigned uu[8];
#pragma unroll
            for (int q = 0; q < 8; ++q) kk[q] = pk[j + q];
#pragma unroll
            for (int q = 0; q < 8; ++q) uu[q] = xb[(size_t)(kk[q] >> 3) * 64 + lane];
#pragma unroll
            for (int q = 0; q < 8; ++q) addpk(acc, kk[q], uu[q]);
        }
        for (; j < end; ++j) {
            int kk = pk[j];
            unsigned u = xb[(size_t)(kk >> 3) * 64 + lane];
            addpk(acc, kk, u);
        }
        // LDS write, swizzled: logical granule g = r*16 + lane/4 -> phys g ^ (i&7)
        int sw = i & 7;
#pragma unroll
        for (int r = 0; r < 8; ++r) {
            int g = r * 16 + (lane >> 2);
            smU[i * 512 + (((g ^ sw) << 2) | (lane & 3))] = packbf(acc[r][0], acc[r][1]);
        }
    }
    __syncthreads();

    // ---- MFMA phase: out[16][128] = relu(A[16][1152] @ Wb^T + b) ----
    // wave wv -> colfrags {2wv, 2wv+1}; A rows shared across waves
    const int r_in = lane & 15, kq = lane >> 4;
    const char* smB = (const char*)smU;
    f32x4 acc2[2];
    acc2[0] = (f32x4){0.f, 0.f, 0.f, 0.f};
    acc2[1] = (f32x4){0.f, 0.f, 0.f, 0.f};
    const int cf0 = wv * 2;
    const unsigned short* B0 = Wb + (size_t)(cf0 * 16 + r_in) * 1152 + kq * 8;
    const unsigned short* B1 = B0 + (size_t)16 * 1152;
    const unsigned short* Xrow = (const unsigned short*)xb + (size_t)(n0 + r_in) * 128 + kq * 8;

#pragma unroll 1
    for (int ks = 0; ks < 36; ++ks) {
        bf16x8 a;
        if (ks < 32) {  // wave-uniform branch
            int g = ks * 4 + kq;
            a = *(const bf16x8*)(smB + r_in * 2048 + ((g ^ (r_in & 7)) << 4));
        } else {
            a = *(const bf16x8*)(Xrow + (ks - 32) * 32);
        }
        acc2[0] = __builtin_amdgcn_mfma_f32_16x16x32_bf16(a, *(const bf16x8*)(B0 + ks * 32),
                                                          acc2[0], 0, 0, 0);
        acc2[1] = __builtin_amdgcn_mfma_f32_16x16x32_bf16(a, *(const bf16x8*)(B1 + ks * 32),
                                                          acc2[1], 0, 0, 0);
    }
    // epilogue (R6-validated D layout): node row = kq*4+reg, col d = cf*16 + r_in
    int nrb = n0 + kq * 4;
#pragma unroll
    for (int c = 0; c < 2; ++c) {
        int d = (cf0 + c) * 16 + r_in;
        float bv = bias[d];
#pragma unroll
        for (int reg = 0; reg < 4; ++reg)
            xbout[(size_t)(nrb + reg) * 128 + d] = f2bf(frelu(acc2[c][reg] + bv));
    }
}

// ---------- column-wise sum/max over final bf16 x ----------
__global__ void k_reduce(const unsigned short* __restrict__ xb, float* __restrict__ gsum,
                         unsigned* __restrict__ gmax) {
    int c = threadIdx.x & 127;
    int half = threadIdx.x >> 7;
    int rbeg = blockIdx.x * 512 + half;
    int rend = min(blockIdx.x * 512 + 512, NN);
    float s = 0.f, m = 0.f;  // post-relu >= 0
    for (int r = rbeg; r < rend; r += 2) {
        float v = bf2f(xb[(size_t)r * 128 + c]);
        s += v;
        m = fmaxf(m, v);
    }
    atomicAdd(&gsum[c], s);
    atomicMax(&gmax[c], __float_as_uint(m));
}

// ---------- heads (single block), fp32 exact on fp32 head weights ----------
__global__ void k_head(const unsigned short* __restrict__ x, const float* __restrict__ gsum,
                       const unsigned* __restrict__ gmaxu, const int* __restrict__ anchor_idx,
                       const float* __restrict__ numeric, const float* __restrict__ boolean_,
                       const int* __restrict__ cats, const float* __restrict__ ce0,
                       const float* __restrict__ ce1, const float* __restrict__ ce2,
                       const float* __restrict__ featW, const float* __restrict__ featb,
                       const float* __restrict__ binW1, const float* __restrict__ binb1,
                       const float* __restrict__ binW2, const float* __restrict__ binb2,
                       const float* __restrict__ mcW1, const float* __restrict__ mcb1,
                       const float* __restrict__ mcW2, const float* __restrict__ mcb2,
                       float* __restrict__ out) {
    __shared__ float comb[432];
    __shared__ float feat[72];
    __shared__ float hb[4][64];
    int t = threadIdx.x;
    int anchor = anchor_idx[0];
    if (t < 128) {
        comb[t] = bf2f(x[(size_t)anchor * 128 + t]);
        comb[128 + t] = gsum[t] * (1.0f / (float)NN);
        comb[256 + t] = __uint_as_float(gmaxu[t]);
    }
    if (t < 32) feat[t] = numeric[t];
    else if (t < 48) feat[t] = boolean_[t - 32];
    else if (t < 56) feat[t] = ce0[cats[0] * 8 + (t - 48)];
    else if (t < 64) feat[t] = ce1[cats[1] * 8 + (t - 56)];
    else if (t < 72) feat[t] = ce2[cats[2] * 8 + (t - 64)];
    __syncthreads();
    if (t < 48) {
        float s = featb[t];
        for (int c = 0; c < 72; ++c) s += featW[t * 72 + c] * feat[c];
        comb[384 + t] = frelu(s);
    }
    __syncthreads();
    {
        int head = t >> 6, u = t & 63;
        const float* W;
        float s;
        if (head < 3) {
            W = binW1 + ((size_t)head * 64 + u) * 432;
            s = binb1[head * 64 + u];
        } else {
            W = mcW1 + (size_t)u * 432;
            s = mcb1[u];
        }
        for (int c = 0; c < 432; ++c) s += W[c] * comb[c];
        hb[head][u] = frelu(s);
    }
    __syncthreads();
    if (t < 3) {
        float s = binb2[t];
        for (int u = 0; u < 64; ++u) s += binW2[t * 64 + u] * hb[t][u];
        out[t] = s;
    } else if (t < 7) {
        int k = t - 3;
        float s = mcb2[k];
        for (int u = 0; u < 64; ++u) s += mcW2[k * 64 + u] * hb[3][u];
        out[3 + k] = s;
    }
}

extern "C" void kernel_launch(void* const* d_in, const int* in_sizes, int n_in,
                              void* d_out, int out_size, void* d_ws, size_t ws_size,
                              hipStream_t stream) {
    const int* ntype = (const int*)d_in[0];
    const int* eidx = (const int*)d_in[1];
    const int* etype = (const int*)d_in[2];
    const int* cats = (const int*)d_in[3];
    const int* anchor = (const int*)d_in[4];
    const float* numeric = (const float*)d_in[5];
    const float* boolean_ = (const float*)d_in[6];
    const float* nemb = (const float*)d_in[7];
    const float* selfW = (const float*)d_in[8];
    const float* selfb = (const float*)d_in[9];
    const float* relW = (const float*)d_in[10];
    const float* ce0 = (const float*)d_in[11];
    const float* ce1 = (const float*)d_in[12];
    const float* ce2 = (const float*)d_in[13];
    const float* featW = (const float*)d_in[14];
    const float* featb = (const float*)d_in[15];
    const float* binW1 = (const float*)d_in[16];
    const float* binb1 = (const float*)d_in[17];
    const float* binW2 = (const float*)d_in[18];
    const float* binb2 = (const float*)d_in[19];
    const float* mcW1 = (const float*)d_in[20];
    const float* mcb1 = (const float*)d_in[21];
    const float* mcW2 = (const float*)d_in[22];
    const float* mcb2 = (const float*)d_in[23];
    float* out = (float*)d_out;

    char* ws = (char*)d_ws;
    size_t off = 0;
    auto alloc = [&](size_t bytes) -> void* {
        void* pp = ws + off;
        off += (bytes + 255) & ~(size_t)255;
        return pp;
    };
    // fixed footprint ~66 MiB (no adaptive buffers)
    unsigned* xbA = (unsigned*)alloc((size_t)NN * 64 * 4);  // bf16 x, packed pairs
    unsigned* xbB = (unsigned*)alloc((size_t)NN * 64 * 4);
    int* rowptr = (int*)alloc((size_t)NN * 4);
    int* partials = (int*)alloc(4096);
    int* pkbuf = (int*)alloc((size_t)EE * 4);
    unsigned short* Wb = (unsigned short*)alloc((size_t)2 * 128 * 1152 * 2);
    float* gsum = (float*)alloc(512);
    unsigned* gmax = (unsigned*)alloc(512);
    (void)in_sizes; (void)n_in; (void)out_size; (void)ws_size;

    hipMemsetAsync(rowptr, 0, (size_t)NN * 4, stream);
    hipMemsetAsync(gsum, 0, 512, stream);
    hipMemsetAsync(gmax, 0, 512, stream);

    k_gather_xb<<<NN * 64 / 256, 256, 0, stream>>>(ntype, nemb, xbA);
    k_count<<<2048, 256, 0, stream>>>(eidx, rowptr);
    int nb1 = (NN + 1023) / 1024;
    k_scan1<<<nb1, 256, 0, stream>>>(rowptr, partials, NN);
    k_scan2<<<1, 1024, 0, stream>>>(partials, nb1);
    k_scan3<<<(NN + 255) / 256, 256, 0, stream>>>(rowptr, partials, NN);
    k_scatter<<<2048, 256, 0, stream>>>(eidx, etype, rowptr, pkbuf);
    k_prepWb<<<2 * 128 * 1152 / 256, 256, 0, stream>>>(relW, selfW, Wb);

    for (int l = 0; l < 2; ++l) {
        const unsigned* xin = l ? xbB : xbA;
        unsigned short* xout = (unsigned short*)(l ? xbA : xbB);
        const unsigned short* Wl = Wb + (size_t)l * 128 * 1152;
        const float* bl = selfb + l * 128;
        k_fused<<<NN / TN, 256, 0, stream>>>(xin, rowptr, pkbuf, Wl, bl, xout);
    }

    // final x is in xbA (layer 1 wrote to it)
    k_reduce<<<(NN + 511) / 512, 256, 0, stream>>>((const unsigned short*)xbA, gsum, gmax);
    k_head<<<1, 256, 0, stream>>>((const unsigned short*)xbA, gsum, gmax, anchor, numeric,
                                  boolean_, cats, ce0, ce1, ce2, featW, featb, binW1, binb1,
                                  binW2, binb2, mcW1, mcb1, mcW2, mcb2, out);
}

// Round 8
// 1746.753 us; speedup vs baseline: 4.8616x; 1.0476x over previous
//
#include <hip/hip_runtime.h>
#include <hip/hip_bf16.h>

// R8 = R7 + coalesced epilogue (LDS C-tile transpose -> full-line 16B stores;
// R7 measured 264 MB HBM WRITE for 25.6 MB logical = ~10x partial-line
// amplification, suspected of thrashing L2/L3 against the gather reads).
// Also: self-K MFMAs hoisted before the barrier; 8/4/1 edge loop.

#define NN 100000
#define EE 3200000
#define TN 16   // nodes per block; NN = 16 * 6250 exactly

typedef __attribute__((ext_vector_type(8))) short bf16x8;
typedef __attribute__((ext_vector_type(4))) float f32x4;

static __device__ __forceinline__ float frelu(float v) { return v > 0.f ? v : 0.f; }

// round-to-nearest-even f32 -> bf16 bits
static __device__ __forceinline__ unsigned short f2bf(float f) {
    unsigned b = __float_as_uint(f);
    return (unsigned short)((b + 0x7fffu + ((b >> 16) & 1u)) >> 16);
}
static __device__ __forceinline__ unsigned packbf(float lo, float hi) {
    return (unsigned)f2bf(lo) | ((unsigned)f2bf(hi) << 16);
}
static __device__ __forceinline__ float bflo(unsigned u) { return __uint_as_float(u << 16); }
static __device__ __forceinline__ float bfhi(unsigned u) { return __uint_as_float(u & 0xffff0000u); }
static __device__ __forceinline__ float bf2f(unsigned short u) {
    return __uint_as_float(((unsigned)u) << 16);
}

// ---------- x0 = bf16(node_emb[node_type_ids]) ----------
__global__ void k_gather_xb(const int* __restrict__ ntype, const float* __restrict__ nemb,
                            unsigned* __restrict__ xb) {
    int i = blockIdx.x * 256 + threadIdx.x;  // exactly N*64 threads; q covers dims 2q,2q+1
    int n = i >> 6, q = i & 63;
    int tt = ntype[n];
    float2 v = ((const float2*)(nemb + (size_t)tt * 128))[q];
    xb[(size_t)n * 64 + q] = packbf(v.x, v.y);
}

// ---------- CSR build keyed by tgt ONLY (N segments, L2-resident atomics) ----------
__global__ void k_count(const int* __restrict__ eidx, int* __restrict__ rowptr) {
    for (int e = blockIdx.x * blockDim.x + threadIdx.x; e < EE; e += gridDim.x * blockDim.x) {
        int2 p = ((const int2*)eidx)[e];
        atomicAdd(&rowptr[p.y], 1);
    }
}

__global__ void k_scan1(int* data, int* partials, int nseg) {
    __shared__ int sd[256];
    int t = threadIdx.x;
    int base = blockIdx.x * 1024 + t * 4;
    int v[4];
#pragma unroll
    for (int k = 0; k < 4; ++k) v[k] = (base + k < nseg) ? data[base + k] : 0;
    int tsum = v[0] + v[1] + v[2] + v[3];
    sd[t] = tsum;
    __syncthreads();
    for (int off = 1; off < 256; off <<= 1) {
        int add = (t >= off) ? sd[t - off] : 0;
        __syncthreads();
        sd[t] += add;
        __syncthreads();
    }
    int run = sd[t] - tsum;
#pragma unroll
    for (int k = 0; k < 4; ++k) {
        if (base + k < nseg) data[base + k] = run;
        run += v[k];
    }
    if (t == 255) partials[blockIdx.x] = sd[255];
}

__global__ void k_scan2(int* partials, int nb) {
    __shared__ int sd[1024];
    int t = threadIdx.x;
    int v = (t < nb) ? partials[t] : 0;
    sd[t] = v;
    __syncthreads();
    for (int off = 1; off < 1024; off <<= 1) {
        int add = (t >= off) ? sd[t - off] : 0;
        __syncthreads();
        sd[t] += add;
        __syncthreads();
    }
    if (t < nb) partials[t] = sd[t] - v;
}

__global__ void k_scan3(int* rowptr, const int* __restrict__ partials, int nseg) {
    int i = blockIdx.x * 256 + threadIdx.x;
    if (i < nseg) rowptr[i] += partials[i >> 10];
}

// scatter packed (src<<3)|rel; rowptr becomes inclusive segment ENDS
__global__ void k_scatter(const int* __restrict__ eidx, const int* __restrict__ etype,
                          int* rowptr, int* __restrict__ pk) {
    for (int e = blockIdx.x * blockDim.x + threadIdx.x; e < EE; e += gridDim.x * blockDim.x) {
        int2 p = ((const int2*)eidx)[e];
        int rel = etype[e];
        int pos = atomicAdd(&rowptr[p.y], 1);
        pk[pos] = (p.x << 3) | rel;
    }
}

// ---------- Wb[l][d][k] bf16: k<1024 -> relW[l][k>>7][d][k&127]; else selfW[l][d][k-1024]
__global__ void k_prepWb(const float* __restrict__ relW, const float* __restrict__ selfW,
                         unsigned short* __restrict__ Wb) {
    int idx = blockIdx.x * 256 + threadIdx.x;  // 2*128*1152 threads
    int k = idx % 1152;
    int d = (idx / 1152) & 127;
    int l = idx / (1152 * 128);
    float v;
    if (k < 1024)
        v = relW[((((size_t)l * 8) + (k >> 7)) * 128 + d) * 128 + (k & 127)];
    else
        v = selfW[((size_t)l * 128 + d) * 128 + (k - 1024)];
    Wb[idx] = f2bf(v);
}

// ---------- fused: gather 16 nodes' 8-rel aggs into swizzled LDS, then MFMA ----------
static __device__ __forceinline__ void addpk(float acc[8][2], int kk, unsigned u) {
    float lo = bflo(u), hi = bfhi(u);
    switch (kk & 7) {  // wave-uniform branch (kk broadcast-loaded)
        case 0: acc[0][0] += lo; acc[0][1] += hi; break;
        case 1: acc[1][0] += lo; acc[1][1] += hi; break;
        case 2: acc[2][0] += lo; acc[2][1] += hi; break;
        case 3: acc[3][0] += lo; acc[3][1] += hi; break;
        case 4: acc[4][0] += lo; acc[4][1] += hi; break;
        case 5: acc[5][0] += lo; acc[5][1] += hi; break;
        case 6: acc[6][0] += lo; acc[6][1] += hi; break;
        case 7: acc[7][0] += lo; acc[7][1] += hi; break;
    }
}

__global__ __launch_bounds__(256) void k_fused(const unsigned* __restrict__ xb,
                                               const int* __restrict__ rowptr,
                                               const int* __restrict__ pk,
                                               const unsigned short* __restrict__ Wb,  // [128][1152]
                                               const float* __restrict__ bias,
                                               unsigned short* __restrict__ xbout) {
    // LDS tile: 16 rows x 1024 bf16 (k=0..1023), 16B-granule XOR swizzle (g ^= row&7)
    // first 4 KB reused as the C-tile after the MFMA loop.
    __shared__ unsigned smU[TN * 512];  // 32 KB
    const int wv = threadIdx.x >> 6, lane = threadIdx.x & 63;
    const int n0 = blockIdx.x * TN;
    const int r_in = lane & 15, kq = lane >> 4;

    // ---- gather phase: wave wv aggregates nodes i = wv*4 .. wv*4+3 ----
    for (int i = wv * 4; i < wv * 4 + 4; ++i) {
        int n = n0 + i;
        int beg = n ? rowptr[n - 1] : 0;
        int end = rowptr[n];
        float acc[8][2];
#pragma unroll
        for (int r = 0; r < 8; ++r) { acc[r][0] = 0.f; acc[r][1] = 0.f; }
        int j = beg;
        for (; j + 8 <= end; j += 8) {  // 8 row-loads in flight
            int kk[8];
            unsigned uu[8];
#pragma unroll
            for (int q = 0; q < 8; ++q) kk[q] = pk[j + q];
#pragma unroll
            for (int q = 0; q < 8; ++q) uu[q] = xb[(size_t)(kk[q] >> 3) * 64 + lane];
#pragma unroll
            for (int q = 0; q < 8; ++q) addpk(acc, kk[q], uu[q]);
        }
        if (j + 4 <= end) {  // 4-deep mid tier
            int kk[4];
            unsigned uu[4];
#pragma unroll
            for (int q = 0; q < 4; ++q) kk[q] = pk[j + q];
#pragma unroll
            for (int q = 0; q < 4; ++q) uu[q] = xb[(size_t)(kk[q] >> 3) * 64 + lane];
#pragma unroll
            for (int q = 0; q < 4; ++q) addpk(acc, kk[q], uu[q]);
            j += 4;
        }
        for (; j < end; ++j) {
            int kk = pk[j];
            unsigned u = xb[(size_t)(kk >> 3) * 64 + lane];
            addpk(acc, kk, u);
        }
        // LDS write, swizzled: logical granule g = r*16 + lane/4 -> phys g ^ (i&7)
        int sw = i & 7;
#pragma unroll
        for (int r = 0; r < 8; ++r) {
            int g = r * 16 + (lane >> 2);
            smU[i * 512 + (((g ^ sw) << 2) | (lane & 3))] = packbf(acc[r][0], acc[r][1]);
        }
    }

    // ---- self-K MFMAs (ks 32..35) BEFORE barrier: A from global, no LDS dep ----
    f32x4 acc2[2];
    acc2[0] = (f32x4){0.f, 0.f, 0.f, 0.f};
    acc2[1] = (f32x4){0.f, 0.f, 0.f, 0.f};
    const int cf0 = wv * 2;
    const unsigned short* B0 = Wb + (size_t)(cf0 * 16 + r_in) * 1152 + kq * 8;
    const unsigned short* B1 = B0 + (size_t)16 * 1152;
    const unsigned short* Xrow = (const unsigned short*)xb + (size_t)(n0 + r_in) * 128 + kq * 8;
#pragma unroll
    for (int ks = 32; ks < 36; ++ks) {
        bf16x8 a = *(const bf16x8*)(Xrow + (ks - 32) * 32);
        acc2[0] = __builtin_amdgcn_mfma_f32_16x16x32_bf16(a, *(const bf16x8*)(B0 + ks * 32),
                                                          acc2[0], 0, 0, 0);
        acc2[1] = __builtin_amdgcn_mfma_f32_16x16x32_bf16(a, *(const bf16x8*)(B1 + ks * 32),
                                                          acc2[1], 0, 0, 0);
    }
    __syncthreads();

    // ---- LDS-K MFMAs (ks 0..31) ----
    const char* smB = (const char*)smU;
#pragma unroll 1
    for (int ks = 0; ks < 32; ++ks) {
        int g = ks * 4 + kq;
        bf16x8 a = *(const bf16x8*)(smB + r_in * 2048 + ((g ^ (r_in & 7)) << 4));
        acc2[0] = __builtin_amdgcn_mfma_f32_16x16x32_bf16(a, *(const bf16x8*)(B0 + ks * 32),
                                                          acc2[0], 0, 0, 0);
        acc2[1] = __builtin_amdgcn_mfma_f32_16x16x32_bf16(a, *(const bf16x8*)(B1 + ks * 32),
                                                          acc2[1], 0, 0, 0);
    }

    // ---- epilogue: C-tile via LDS -> coalesced full-line stores ----
    __syncthreads();  // all waves done reading A-tile; reuse smU[0..1023] as C (4 KB)
    unsigned short* Cs = (unsigned short*)smU;
#pragma unroll
    for (int c = 0; c < 2; ++c) {
        int d = (cf0 + c) * 16 + r_in;
        float bv = bias[d];
#pragma unroll
        for (int reg = 0; reg < 4; ++reg)
            Cs[(kq * 4 + reg) * 128 + d] = f2bf(frelu(acc2[c][reg] + bv));
    }
    __syncthreads();
    {   // 16 rows x 256B, one 16B granule per thread, fully coalesced
        int row = threadIdx.x >> 4, g16 = threadIdx.x & 15;
        int4 v = *(const int4*)((const char*)Cs + row * 256 + g16 * 16);
        *(int4*)((char*)xbout + (size_t)(n0 + row) * 256 + g16 * 16) = v;
    }
}

// ---------- column-wise sum/max over final bf16 x ----------
__global__ void k_reduce(const unsigned short* __restrict__ xb, float* __restrict__ gsum,
                         unsigned* __restrict__ gmax) {
    int c = threadIdx.x & 127;
    int half = threadIdx.x >> 7;
    int rbeg = blockIdx.x * 512 + half;
    int rend = min(blockIdx.x * 512 + 512, NN);
    float s = 0.f, m = 0.f;  // post-relu >= 0
    for (int r = rbeg; r < rend; r += 2) {
        float v = bf2f(xb[(size_t)r * 128 + c]);
        s += v;
        m = fmaxf(m, v);
    }
    atomicAdd(&gsum[c], s);
    atomicMax(&gmax[c], __float_as_uint(m));
}

// ---------- heads (single block), fp32 exact on fp32 head weights ----------
__global__ void k_head(const unsigned short* __restrict__ x, const float* __restrict__ gsum,
                       const unsigned* __restrict__ gmaxu, const int* __restrict__ anchor_idx,
                       const float* __restrict__ numeric, const float* __restrict__ boolean_,
                       const int* __restrict__ cats, const float* __restrict__ ce0,
                       const float* __restrict__ ce1, const float* __restrict__ ce2,
                       const float* __restrict__ featW, const float* __restrict__ featb,
                       const float* __restrict__ binW1, const float* __restrict__ binb1,
                       const float* __restrict__ binW2, const float* __restrict__ binb2,
                       const float* __restrict__ mcW1, const float* __restrict__ mcb1,
                       const float* __restrict__ mcW2, const float* __restrict__ mcb2,
                       float* __restrict__ out) {
    __shared__ float comb[432];
    __shared__ float feat[72];
    __shared__ float hb[4][64];
    int t = threadIdx.x;
    int anchor = anchor_idx[0];
    if (t < 128) {
        comb[t] = bf2f(x[(size_t)anchor * 128 + t]);
        comb[128 + t] = gsum[t] * (1.0f / (float)NN);
        comb[256 + t] = __uint_as_float(gmaxu[t]);
    }
    if (t < 32) feat[t] = numeric[t];
    else if (t < 48) feat[t] = boolean_[t - 32];
    else if (t < 56) feat[t] = ce0[cats[0] * 8 + (t - 48)];
    else if (t < 64) feat[t] = ce1[cats[1] * 8 + (t - 56)];
    else if (t < 72) feat[t] = ce2[cats[2] * 8 + (t - 64)];
    __syncthreads();
    if (t < 48) {
        float s = featb[t];
        for (int c = 0; c < 72; ++c) s += featW[t * 72 + c] * feat[c];
        comb[384 + t] = frelu(s);
    }
    __syncthreads();
    {
        int head = t >> 6, u = t & 63;
        const float* W;
        float s;
        if (head < 3) {
            W = binW1 + ((size_t)head * 64 + u) * 432;
            s = binb1[head * 64 + u];
        } else {
            W = mcW1 + (size_t)u * 432;
            s = mcb1[u];
        }
        for (int c = 0; c < 432; ++c) s += W[c] * comb[c];
        hb[head][u] = frelu(s);
    }
    __syncthreads();
    if (t < 3) {
        float s = binb2[t];
        for (int u = 0; u < 64; ++u) s += binW2[t * 64 + u] * hb[t][u];
        out[t] = s;
    } else if (t < 7) {
        int k = t - 3;
        float s = mcb2[k];
        for (int u = 0; u < 64; ++u) s += mcW2[k * 64 + u] * hb[3][u];
        out[3 + k] = s;
    }
}

extern "C" void kernel_launch(void* const* d_in, const int* in_sizes, int n_in,
                              void* d_out, int out_size, void* d_ws, size_t ws_size,
                              hipStream_t stream) {
    const int* ntype = (const int*)d_in[0];
    const int* eidx = (const int*)d_in[1];
    const int* etype = (const int*)d_in[2];
    const int* cats = (const int*)d_in[3];
    const int* anchor = (const int*)d_in[4];
    const float* numeric = (const float*)d_in[5];
    const float* boolean_ = (const float*)d_in[6];
    const float* nemb = (const float*)d_in[7];
    const float* selfW = (const float*)d_in[8];
    const float* selfb = (const float*)d_in[9];
    const float* relW = (const float*)d_in[10];
    const float* ce0 = (const float*)d_in[11];
    const float* ce1 = (const float*)d_in[12];
    const float* ce2 = (const float*)d_in[13];
    const float* featW = (const float*)d_in[14];
    const float* featb = (const float*)d_in[15];
    const float* binW1 = (const float*)d_in[16];
    const float* binb1 = (const float*)d_in[17];
    const float* binW2 = (const float*)d_in[18];
    const float* binb2 = (const float*)d_in[19];
    const float* mcW1 = (const float*)d_in[20];
    const float* mcb1 = (const float*)d_in[21];
    const float* mcW2 = (const float*)d_in[22];
    const float* mcb2 = (const float*)d_in[23];
    float* out = (float*)d_out;

    char* ws = (char*)d_ws;
    size_t off = 0;
    auto alloc = [&](size_t bytes) -> void* {
        void* pp = ws + off;
        off += (bytes + 255) & ~(size_t)255;
        return pp;
    };
    // fixed footprint ~66 MiB (no adaptive buffers)
    unsigned* xbA = (unsigned*)alloc((size_t)NN * 64 * 4);  // bf16 x, packed pairs
    unsigned* xbB = (unsigned*)alloc((size_t)NN * 64 * 4);
    int* rowptr = (int*)alloc((size_t)NN * 4);
    int* partials = (int*)alloc(4096);
    int* pkbuf = (int*)alloc((size_t)EE * 4);
    unsigned short* Wb = (unsigned short*)alloc((size_t)2 * 128 * 1152 * 2);
    float* gsum = (float*)alloc(512);
    unsigned* gmax = (unsigned*)alloc(512);
    (void)in_sizes; (void)n_in; (void)out_size; (void)ws_size;

    hipMemsetAsync(rowptr, 0, (size_t)NN * 4, stream);
    hipMemsetAsync(gsum, 0, 512, stream);
    hipMemsetAsync(gmax, 0, 512, stream);

    k_gather_xb<<<NN * 64 / 256, 256, 0, stream>>>(ntype, nemb, xbA);
    k_count<<<2048, 256, 0, stream>>>(eidx, rowptr);
    int nb1 = (NN + 1023) / 1024;
    k_scan1<<<nb1, 256, 0, stream>>>(rowptr, partials, NN);
    k_scan2<<<1, 1024, 0, stream>>>(partials, nb1);
    k_scan3<<<(NN + 255) / 256, 256, 0, stream>>>(rowptr, partials, NN);
    k_scatter<<<2048, 256, 0, stream>>>(eidx, etype, rowptr, pkbuf);
    k_prepWb<<<2 * 128 * 1152 / 256, 256, 0, stream>>>(relW, selfW, Wb);

    for (int l = 0; l < 2; ++l) {
        const unsigned* xin = l ? xbB : xbA;
        unsigned short* xout = (unsigned short*)(l ? xbA : xbB);
        const unsigned short* Wl = Wb + (size_t)l * 128 * 1152;
        const float* bl = selfb + l * 128;
        k_fused<<<NN / TN, 256, 0, stream>>>(xin, rowptr, pkbuf, Wl, bl, xout);
    }

    // final x is in xbA (layer 1 wrote to it)
    k_reduce<<<(NN + 511) / 512, 256, 0, stream>>>((const unsigned short*)xbA, gsum, gmax);
    k_head<<<1, 256, 0, stream>>>((const unsigned short*)xbA, gsum, gmax, anchor, numeric,
                                  boolean_, cats, ce0, ce1, ce2, featW, featb, binW1, binb1,
                                  binW2, binb2, mcW1, mcb1, mcW2, mcb2, out);
}